// Round 1
// baseline (2212.622 us; speedup 1.0000x reference)
//
#include <hip/hip_runtime.h>
#include <math.h>

// ---------------- histogram of labels ----------------
__global__ void k_hist(const int* __restrict__ labels, int* __restrict__ hist, int B) {
    int i = blockIdx.x * blockDim.x + threadIdx.x;
    if (i < B) atomicAdd(&hist[labels[i]], 1);
}

// ---------------- sum of freqs = class_freqs + hist ----------------
__global__ void k_freqsum(const float* __restrict__ class_freqs, const int* __restrict__ hist,
                          float* __restrict__ sum_freq, int C) {
    int i = blockIdx.x * blockDim.x + threadIdx.x;
    float v = 0.f;
    if (i < C) v = class_freqs[i] + (float)hist[i];
    #pragma unroll
    for (int off = 32; off > 0; off >>= 1) v += __shfl_down(v, off, 64);
    __shared__ float smem[4];
    int lane = threadIdx.x & 63, wid = threadIdx.x >> 6;
    if (lane == 0) smem[wid] = v;
    __syncthreads();
    if (threadIdx.x == 0)
        atomicAdd(sum_freq, smem[0] + smem[1] + smem[2] + smem[3]);
}

// ---------------- per-class weight ----------------
// reweighed = beta*(1-p) + (1-beta)*p = beta + p*(1 - 2*beta)
__global__ void k_weights(const float* __restrict__ class_freqs, const int* __restrict__ hist,
                          const float* __restrict__ beta, const float* __restrict__ sum_freq,
                          float* __restrict__ w, int C) {
    int i = blockIdx.x * blockDim.x + threadIdx.x;
    if (i < C) {
        float p = (class_freqs[i] + (float)hist[i]) / sum_freq[0];
        float b = beta[i];
        w[i] = b + p * (1.f - 2.f * b);
    }
}

// ---------------- main: one block per row, online softmax ----------------
__global__ __launch_bounds__(256) void k_loss(const float* __restrict__ logits,
                                              const int* __restrict__ labels,
                                              const float* __restrict__ w,
                                              float* __restrict__ accum, // [0]=sum_wnll [1]=sum_w
                                              int C) {
    const int row = blockIdx.x;
    const float* rowp = logits + (size_t)row * C;
    const float4* row4 = reinterpret_cast<const float4*>(rowp);
    const int n4 = C >> 2;

    float m = -3.0e38f, s = 0.f;
    for (int idx = threadIdx.x; idx < n4; idx += 256) {
        float4 v = row4[idx];
        float mv = fmaxf(fmaxf(v.x, v.y), fmaxf(v.z, v.w));
        float mn = fmaxf(m, mv);
        s = s * __expf(m - mn)
          + __expf(v.x - mn) + __expf(v.y - mn)
          + __expf(v.z - mn) + __expf(v.w - mn);
        m = mn;
    }
    // scalar remainder (C % 4 != 0 safety; no-op for C=10000)
    for (int idx = (n4 << 2) + threadIdx.x; idx < C; idx += 256) {
        float v = rowp[idx];
        float mn = fmaxf(m, v);
        s = s * __expf(m - mn) + __expf(v - mn);
        m = mn;
    }

    // wave64 reduction of (m, s)
    #pragma unroll
    for (int off = 32; off > 0; off >>= 1) {
        float mo = __shfl_down(m, off, 64);
        float so = __shfl_down(s, off, 64);
        float mn = fmaxf(m, mo);
        s = s * __expf(m - mn) + so * __expf(mo - mn);
        m = mn;
    }
    __shared__ float sm[4], ss[4];
    int lane = threadIdx.x & 63, wid = threadIdx.x >> 6;
    if (lane == 0) { sm[wid] = m; ss[wid] = s; }
    __syncthreads();
    if (threadIdx.x == 0) {
        float mm = sm[0], sS = ss[0];
        #pragma unroll
        for (int k = 1; k < 4; ++k) {
            float mn = fmaxf(mm, sm[k]);
            sS = sS * __expf(mm - mn) + ss[k] * __expf(sm[k] - mn);
            mm = mn;
        }
        int lab = labels[row];
        float x = rowp[lab];
        float nll = logf(sS) + mm - x;      // logsumexp - x_label
        float wg = w[lab];
        atomicAdd(&accum[0], wg * nll);
        atomicAdd(&accum[1], wg);
    }
}

// ---------------- finisher ----------------
__global__ void k_final(const float* __restrict__ accum, float* __restrict__ out) {
    out[0] = accum[0] / accum[1];
}

extern "C" void kernel_launch(void* const* d_in, const int* in_sizes, int n_in,
                              void* d_out, int out_size, void* d_ws, size_t ws_size,
                              hipStream_t stream) {
    const float* logits      = (const float*)d_in[0];
    const int*   labels      = (const int*)d_in[1];
    const float* class_freqs = (const float*)d_in[2];
    const float* beta        = (const float*)d_in[3];

    const int B = in_sizes[1];
    const int C = in_sizes[2];

    // workspace layout: hist[C] (int) | w[C] (float) | accum[3] (float)
    int*   hist  = (int*)d_ws;
    float* w     = (float*)d_ws + C;
    float* accum = (float*)d_ws + 2 * C;       // [0]=sum_wnll [1]=sum_w [2]=sum_freq
    float* sum_freq = accum + 2;

    // zero hist + accumulators (ws is poisoned 0xAA before every launch)
    hipMemsetAsync(d_ws, 0, (size_t)(2 * C + 3) * sizeof(float), stream);

    k_hist<<<(B + 255) / 256, 256, 0, stream>>>(labels, hist, B);
    k_freqsum<<<(C + 255) / 256, 256, 0, stream>>>(class_freqs, hist, sum_freq, C);
    k_weights<<<(C + 255) / 256, 256, 0, stream>>>(class_freqs, hist, beta, sum_freq, w, C);
    k_loss<<<B, 256, 0, stream>>>(logits, labels, w, accum, C);
    k_final<<<1, 1, 0, stream>>>(accum, (float*)d_out);
}